// Round 3
// baseline (1863.098 us; speedup 1.0000x reference)
//
#include <hip/hip_runtime.h>

#define N_NODES 50000
#define E_EDGES 262144

typedef __attribute__((ext_vector_type(8))) short bf16x8;
typedef __attribute__((ext_vector_type(4))) float f32x4;

union V16 { uint4 u; bf16x8 h; };

__device__ __forceinline__ unsigned rne_pack(float a, float b) {
  unsigned ua = __float_as_uint(a); ua += 0x7fffu + ((ua >> 16) & 1u);
  unsigned ub = __float_as_uint(b); ub += 0x7fffu + ((ub >> 16) & 1u);
  return (ua >> 16) | (ub & 0xffff0000u);
}
__device__ __forceinline__ float bflo(unsigned u) { return __uint_as_float(u << 16); }
__device__ __forceinline__ float bfhi(unsigned u) { return __uint_as_float(u & 0xffff0000u); }
// (bits(a)>>16) | (bits(b)&0xffff0000) in one v_perm_b32
__device__ __forceinline__ unsigned perm_pack(float a, float b) {
  return __builtin_amdgcn_perm(__float_as_uint(b), __float_as_uint(a), 0x07060302u);
}
__device__ __forceinline__ void async_gather16(const void* gptr, void* lptr) {
  __builtin_amdgcn_global_load_lds(
      (const __attribute__((address_space(1))) void*)gptr,
      (__attribute__((address_space(3))) void*)lptr, 16, 0, 0);
}

// ---- prep: node_repr fp32 -> bf16 (RNE) ----
__global__ void cvt_node_kernel(const float* __restrict__ x, unsigned short* __restrict__ y) {
  int i = (blockIdx.x * 256 + threadIdx.x) * 8;
  float4 f0 = *(const float4*)(x + i);
  float4 f1 = *(const float4*)(x + i + 4);
  uint4 o;
  o.x = rne_pack(f0.x, f0.y);
  o.y = rne_pack(f0.z, f0.w);
  o.z = rne_pack(f1.x, f1.y);
  o.w = rne_pack(f1.z, f1.w);
  *(uint4*)(y + i) = o;
}

// ---- prep: W1 (1024x512 row-major in->out) -> W1pp2 bf16, 16-B units laid out
// [step(8)][sq=s*4+quad(16)][col(512)], unit = W1[k0..k0+8)[col], k0=s*256+step*32+quad*8
__global__ void prep_w1pp2_kernel(const float* __restrict__ w1, unsigned short* __restrict__ w1pp2) {
  int t = blockIdx.x * 256 + threadIdx.x;  // 65536 units
  int step = t >> 13;
  int rem = t & 8191;
  int sq = rem >> 9;
  int col = rem & 511;
  int s = sq >> 2, qd = sq & 3;
  int k0 = s * 256 + step * 32 + qd * 8;
  float f[8];
#pragma unroll
  for (int i = 0; i < 8; ++i) f[i] = w1[(size_t)(k0 + i) * 512 + col];
  uint4 o;
  o.x = rne_pack(f[0], f[1]);
  o.y = rne_pack(f[2], f[3]);
  o.z = rne_pack(f[4], f[5]);
  o.w = rne_pack(f[6], f[7]);
  *(uint4*)(w1pp2 + (size_t)t * 8) = o;
}

// ---- prep: out[e][c] = b2[c] ----
__global__ void init_out_kernel(float* __restrict__ out, const float* __restrict__ b2) {
  int i = blockIdx.x * 256 + threadIdx.x;
  float2 v; v.x = b2[0]; v.y = b2[1];
  *(float2*)(out + (size_t)i * 2) = v;
}

// ---- main fused kernel: block = 64 edges x 256 cols (4 waves, the PROVEN 112-VGPR
//      body), but A staged in TWO K-chunks of 128 elems -> LDS 32 KB (was 64) ->
//      4 blocks/CU = 4 waves/SIMD (was 2). 3 barriers total. B streamed, fine vmcnt.
//      History: (512,4)->VGPR64 spilled 5.6GB; (512,2)->cap128 still spilled (acc=64
//      regs + 512-col tile needs >128). 256-thr body compiles to 112 VGPR: keep it. ----
__global__ __launch_bounds__(256, 4) void edge_mlp_kernel(
    const unsigned short* __restrict__ nodeb,  // [50000][256] bf16
    const unsigned short* __restrict__ w1pp2,  // repacked W1 (see prep)
    const int* __restrict__ src,
    const int* __restrict__ dst,
    const float* __restrict__ b1,
    const float* __restrict__ w2,   // [512][2] fp32
    float* __restrict__ out) {      // [E][2] fp32, pre-init with b2
  // Per chunk: hi: [0,16K) — 64 edges x 256 B; hj: [16K,32K)
  // 16-B unit slot for (e, u): e*256 + (u ^ (e&7))*16, u = in-chunk unit 0..15
  __shared__ char smem[32768];

  const int tid = threadIdx.x;
  const int wid = tid >> 6;      // 0..3
  const int lane = tid & 63;
  const int quad = lane >> 4;
  const int l16 = lane & 15;
  const int bx = blockIdx.x;
  // XCD swizzle: xc = bx&7; n-siblings + neighbor m-tiles share an XCD
  const int xc = bx & 7;
  const int t2 = bx >> 3;
  const int n_half = t2 & 1;                 // 0..1 (256-col halves)
  const int m_idx = (t2 >> 1) * 8 + xc;      // 0..4095 (64-edge tiles)
  const int row0 = m_idx * 64;
  const int n0 = n_half * 256 + wid * 64;

  const char* nodeB = (const char*)nodeb;
  const char* w1B = (const char*)w1pp2;

  // ---- B register-load offsets: (s*4+quad)*8192 + (n0+l16)*16 (+ step*131072) ----
  unsigned bOff[4];
#pragma unroll
  for (int s = 0; s < 4; ++s)
    bOff[s] = (unsigned)((s * 4 + quad) * 8192 + (n0 + l16) * 16);
  const char* w1s = w1B;

  // ---- A reader base: byte = (mt*16+l16)*256 + (((st4*4+q)^(l16&7))<<4) ----
  const unsigned aXor = (unsigned)(l16 & 7);
  const unsigned aBase = (unsigned)(l16 * 256);

  f32x4 acc[4][4];
#pragma unroll
  for (int mt = 0; mt < 4; ++mt)
#pragma unroll
    for (int nt = 0; nt < 4; ++nt)
      acc[mt][nt] = (f32x4){0.f, 0.f, 0.f, 0.f};

  // ---- chunked A staging: chunk ck stages bytes [ck*256, ck*256+256) of each
  //      node row (16 units). Slot v = c*256+tid; e = c*16 + (tid>>4); u = tid&15.
  //      Linear LDS dest (base+lane*16); XOR swizzle carried on the SOURCE addr. ----
  auto stage_chunk = [&](int ck) {
    const int eh = tid >> 4;  // 0..15
    const unsigned wsw = (unsigned)(((tid & 15) ^ (eh & 7)) << 4) + (unsigned)(ck * 256);
#pragma unroll
    for (int c = 0; c < 4; ++c) {
      int e = c * 16 + eh;
      unsigned so = ((unsigned)src[row0 + e] << 9) + wsw;
      unsigned do_ = ((unsigned)dst[row0 + e] << 9) + wsw;
      async_gather16(nodeB + so, smem + c * 4096 + wid * 1024);
      async_gather16(nodeB + do_, smem + 16384 + c * 4096 + wid * 1024);
    }
  };

  // ---- one K-step (in-chunk index st4 = 0..3): identical math to proven body ----
  auto kstep = [&](int st4) {
    V16 bf[4][4];
#pragma unroll
    for (int s = 0; s < 4; ++s)
#pragma unroll
      for (int nt = 0; nt < 4; ++nt)
        bf[s][nt].u = *(const uint4*)(w1s + bOff[s] + nt * 256);
    const unsigned stq = (unsigned)(st4 * 4 + quad);
    V16 hi[4], hj[4];
#pragma unroll
    for (int mt = 0; mt < 4; ++mt) {
      unsigned ao = (unsigned)(mt * 16 * 256) + aBase + ((stq ^ aXor) << 4);
      hi[mt].u = *(const uint4*)(smem + ao);
      hj[mt].u = *(const uint4*)(smem + 16384 + ao);
    }
#pragma unroll
    for (int sl = 0; sl < 2; ++sl) {
#pragma unroll
      for (int mt = 0; mt < 4; ++mt) {
        bf16x8 af = (sl == 0) ? hi[mt].h : hj[mt].h;
#pragma unroll
        for (int nt = 0; nt < 4; ++nt)
          acc[mt][nt] = __builtin_amdgcn_mfma_f32_16x16x32_bf16(af, bf[sl][nt].h, acc[mt][nt], 0, 0, 0);
      }
    }
#pragma unroll
    for (int mt = 0; mt < 4; ++mt) {
      const unsigned hw[4] = {hi[mt].u.x, hi[mt].u.y, hi[mt].u.z, hi[mt].u.w};
      const unsigned jw[4] = {hj[mt].u.x, hj[mt].u.y, hj[mt].u.z, hj[mt].u.w};
      unsigned d[4], pr[4];
#pragma unroll
      for (int w = 0; w < 4; ++w) {
        float i0 = bflo(hw[w]), i1 = bfhi(hw[w]);
        float j0 = bflo(jw[w]), j1 = bfhi(jw[w]);
        d[w] = perm_pack(i0 - j0, i1 - j1) & 0x7fff7fffu;
        pr[w] = perm_pack(i0 * j0, i1 * j1);
      }
      V16 a2, a3;
      a2.u = make_uint4(d[0], d[1], d[2], d[3]);
      a3.u = make_uint4(pr[0], pr[1], pr[2], pr[3]);
#pragma unroll
      for (int nt = 0; nt < 4; ++nt)
        acc[mt][nt] = __builtin_amdgcn_mfma_f32_16x16x32_bf16(a2.h, bf[2][nt].h, acc[mt][nt], 0, 0, 0);
#pragma unroll
      for (int nt = 0; nt < 4; ++nt)
        acc[mt][nt] = __builtin_amdgcn_mfma_f32_16x16x32_bf16(a3.h, bf[3][nt].h, acc[mt][nt], 0, 0, 0);
    }
    w1s += 131072;
  };

  stage_chunk(0);
  __syncthreads();
#pragma unroll 2
  for (int st4 = 0; st4 < 4; ++st4) kstep(st4);

  __syncthreads();       // all reads of chunk 0 done
  stage_chunk(1);
  __syncthreads();       // chunk 1 visible (compiler drains vmcnt here)
#pragma unroll 2
  for (int st4 = 0; st4 < 4; ++st4) kstep(st4);

  // ---- epilogue: bias + ReLU + W2, 16-lane shuffle reduce, atomic out ----
#pragma unroll
  for (int mt = 0; mt < 4; ++mt) {
    float pc0[4] = {0.f, 0.f, 0.f, 0.f};
    float pc1[4] = {0.f, 0.f, 0.f, 0.f};
#pragma unroll
    for (int nt = 0; nt < 4; ++nt) {
      int gc = n0 + nt * 16 + l16;
      float b1v = b1[gc];
      float w20 = w2[gc * 2 + 0];
      float w21 = w2[gc * 2 + 1];
#pragma unroll
      for (int r = 0; r < 4; ++r) {
        float v = fmaxf(acc[mt][nt][r] + b1v, 0.f);
        pc0[r] = fmaf(v, w20, pc0[r]);
        pc1[r] = fmaf(v, w21, pc1[r]);
      }
    }
#pragma unroll
    for (int r = 0; r < 4; ++r) {
      float s0 = pc0[r], s1 = pc1[r];
#pragma unroll
      for (int off = 1; off < 16; off <<= 1) {
        s0 += __shfl_xor(s0, off);
        s1 += __shfl_xor(s1, off);
      }
      int e = row0 + mt * 16 + quad * 4 + r;  // C/D: row = quad*4 + r
      if (l16 == 0) unsafeAtomicAdd(&out[(size_t)e * 2 + 0], s0);
      if (l16 == 1) unsafeAtomicAdd(&out[(size_t)e * 2 + 1], s1);
    }
  }
}

extern "C" void kernel_launch(void* const* d_in, const int* in_sizes, int n_in,
                              void* d_out, int out_size, void* d_ws, size_t ws_size,
                              hipStream_t stream) {
  const float* node = (const float*)d_in[0];
  const int* src = (const int*)d_in[1];
  const int* dst = (const int*)d_in[2];
  const float* W1 = (const float*)d_in[3];
  const float* b1 = (const float*)d_in[4];
  const float* W2 = (const float*)d_in[5];
  const float* b2 = (const float*)d_in[6];
  float* out = (float*)d_out;

  unsigned short* nodeb = (unsigned short*)d_ws;                      // 25,600,000 B
  unsigned short* w1pp2 = (unsigned short*)((char*)d_ws + 25600000);  // 1,048,576 B

  cvt_node_kernel<<<6250, 256, 0, stream>>>(node, nodeb);
  prep_w1pp2_kernel<<<256, 256, 0, stream>>>(W1, w1pp2);
  init_out_kernel<<<1024, 256, 0, stream>>>(out, b2);
  edge_mlp_kernel<<<8192, 256, 0, stream>>>(nodeb, w1pp2, src, dst, b1, W2, out);
}

// Round 4
// 468.734 us; speedup vs baseline: 3.9747x; 3.9747x over previous
//
#include <hip/hip_runtime.h>

#define N_NODES 50000
#define E_EDGES 262144

typedef __attribute__((ext_vector_type(8))) short bf16x8;
typedef __attribute__((ext_vector_type(4))) float f32x4;

union V16 { uint4 u; bf16x8 h; };

__device__ __forceinline__ unsigned rne_pack(float a, float b) {
  unsigned ua = __float_as_uint(a); ua += 0x7fffu + ((ua >> 16) & 1u);
  unsigned ub = __float_as_uint(b); ub += 0x7fffu + ((ub >> 16) & 1u);
  return (ua >> 16) | (ub & 0xffff0000u);
}
__device__ __forceinline__ float bflo(unsigned u) { return __uint_as_float(u << 16); }
__device__ __forceinline__ float bfhi(unsigned u) { return __uint_as_float(u & 0xffff0000u); }
// (bits(a)>>16) | (bits(b)&0xffff0000) in one v_perm_b32
__device__ __forceinline__ unsigned perm_pack(float a, float b) {
  return __builtin_amdgcn_perm(__float_as_uint(b), __float_as_uint(a), 0x07060302u);
}
__device__ __forceinline__ void async_gather16(const void* gptr, void* lptr) {
  __builtin_amdgcn_global_load_lds(
      (const __attribute__((address_space(1))) void*)gptr,
      (__attribute__((address_space(3))) void*)lptr, 16, 0, 0);
}

// ---- prep: node_repr fp32 -> bf16 (RNE) ----
__global__ void cvt_node_kernel(const float* __restrict__ x, unsigned short* __restrict__ y) {
  int i = (blockIdx.x * 256 + threadIdx.x) * 8;
  float4 f0 = *(const float4*)(x + i);
  float4 f1 = *(const float4*)(x + i + 4);
  uint4 o;
  o.x = rne_pack(f0.x, f0.y);
  o.y = rne_pack(f0.z, f0.w);
  o.z = rne_pack(f1.x, f1.y);
  o.w = rne_pack(f1.z, f1.w);
  *(uint4*)(y + i) = o;
}

// ---- prep: W1 (1024x512 row-major in->out) -> W1pp2 bf16, 16-B units laid out
// [step(8)][sq=s*4+quad(16)][col(512)], unit = W1[k0..k0+8)[col], k0=s*256+step*32+quad*8
__global__ void prep_w1pp2_kernel(const float* __restrict__ w1, unsigned short* __restrict__ w1pp2) {
  int t = blockIdx.x * 256 + threadIdx.x;  // 65536 units
  int step = t >> 13;
  int rem = t & 8191;
  int sq = rem >> 9;
  int col = rem & 511;
  int s = sq >> 2, qd = sq & 3;
  int k0 = s * 256 + step * 32 + qd * 8;
  float f[8];
#pragma unroll
  for (int i = 0; i < 8; ++i) f[i] = w1[(size_t)(k0 + i) * 512 + col];
  uint4 o;
  o.x = rne_pack(f[0], f[1]);
  o.y = rne_pack(f[2], f[3]);
  o.z = rne_pack(f[4], f[5]);
  o.w = rne_pack(f[6], f[7]);
  *(uint4*)(w1pp2 + (size_t)t * 8) = o;
}

// ---- prep: out[e][c] = b2[c] ----
__global__ void init_out_kernel(float* __restrict__ out, const float* __restrict__ b2) {
  int i = blockIdx.x * 256 + threadIdx.x;
  float2 v; v.x = b2[0]; v.y = b2[1];
  *(float2*)(out + (size_t)i * 2) = v;
}

// ---- main fused kernel: block = 64 edges x 256 cols (4 waves, proven 112-VGPR body),
//      A staged in TWO K-chunks of 128 elems -> LDS 32 KB -> VGPR(112) allows
//      4 waves/SIMD, LDS allows 5 blocks/CU => ~4 blocks/CU resident (2x baseline).
//      NO second __launch_bounds__ arg: any value we tried (4 with 256 or 512 thr)
//      forced VGPR=64 -> acc spills -> 5.5 GB scratch writes -> 5x regression.
//      The natural allocation for this body is 112 VGPR, which is what we want. ----
__global__ __launch_bounds__(256) void edge_mlp_kernel(
    const unsigned short* __restrict__ nodeb,  // [50000][256] bf16
    const unsigned short* __restrict__ w1pp2,  // repacked W1 (see prep)
    const int* __restrict__ src,
    const int* __restrict__ dst,
    const float* __restrict__ b1,
    const float* __restrict__ w2,   // [512][2] fp32
    float* __restrict__ out) {      // [E][2] fp32, pre-init with b2
  // Per chunk: hi: [0,16K) — 64 edges x 256 B; hj: [16K,32K)
  // 16-B unit slot for (e, u): e*256 + (u ^ (e&7))*16, u = in-chunk unit 0..15
  __shared__ char smem[32768];

  const int tid = threadIdx.x;
  const int wid = tid >> 6;      // 0..3
  const int lane = tid & 63;
  const int quad = lane >> 4;
  const int l16 = lane & 15;
  const int bx = blockIdx.x;
  // XCD swizzle: xc = bx&7; n-siblings + neighbor m-tiles share an XCD
  const int xc = bx & 7;
  const int t2 = bx >> 3;
  const int n_half = t2 & 1;                 // 0..1 (256-col halves)
  const int m_idx = (t2 >> 1) * 8 + xc;      // 0..4095 (64-edge tiles)
  const int row0 = m_idx * 64;
  const int n0 = n_half * 256 + wid * 64;

  const char* nodeB = (const char*)nodeb;
  const char* w1B = (const char*)w1pp2;

  // ---- B register-load offsets: (s*4+quad)*8192 + (n0+l16)*16 (+ step*131072) ----
  unsigned bOff[4];
#pragma unroll
  for (int s = 0; s < 4; ++s)
    bOff[s] = (unsigned)((s * 4 + quad) * 8192 + (n0 + l16) * 16);
  const char* w1s = w1B;

  // ---- A reader base: byte = (mt*16+l16)*256 + (((st4*4+q)^(l16&7))<<4) ----
  const unsigned aXor = (unsigned)(l16 & 7);
  const unsigned aBase = (unsigned)(l16 * 256);

  f32x4 acc[4][4];
#pragma unroll
  for (int mt = 0; mt < 4; ++mt)
#pragma unroll
    for (int nt = 0; nt < 4; ++nt)
      acc[mt][nt] = (f32x4){0.f, 0.f, 0.f, 0.f};

  // ---- chunked A staging: chunk ck stages bytes [ck*256, ck*256+256) of each
  //      node row (16 units). Slot v = c*256+tid; e = c*16 + (tid>>4); u = tid&15.
  //      Linear LDS dest (base+lane*16); XOR swizzle carried on the SOURCE addr. ----
  auto stage_chunk = [&](int ck) {
    const int eh = tid >> 4;  // 0..15
    const unsigned wsw = (unsigned)(((tid & 15) ^ (eh & 7)) << 4) + (unsigned)(ck * 256);
#pragma unroll
    for (int c = 0; c < 4; ++c) {
      int e = c * 16 + eh;
      unsigned so = ((unsigned)src[row0 + e] << 9) + wsw;
      unsigned do_ = ((unsigned)dst[row0 + e] << 9) + wsw;
      async_gather16(nodeB + so, smem + c * 4096 + wid * 1024);
      async_gather16(nodeB + do_, smem + 16384 + c * 4096 + wid * 1024);
    }
  };

  // ---- one K-step (in-chunk index st4 = 0..3): identical math to proven body ----
  auto kstep = [&](int st4) {
    V16 bf[4][4];
#pragma unroll
    for (int s = 0; s < 4; ++s)
#pragma unroll
      for (int nt = 0; nt < 4; ++nt)
        bf[s][nt].u = *(const uint4*)(w1s + bOff[s] + nt * 256);
    const unsigned stq = (unsigned)(st4 * 4 + quad);
    V16 hi[4], hj[4];
#pragma unroll
    for (int mt = 0; mt < 4; ++mt) {
      unsigned ao = (unsigned)(mt * 16 * 256) + aBase + ((stq ^ aXor) << 4);
      hi[mt].u = *(const uint4*)(smem + ao);
      hj[mt].u = *(const uint4*)(smem + 16384 + ao);
    }
#pragma unroll
    for (int sl = 0; sl < 2; ++sl) {
#pragma unroll
      for (int mt = 0; mt < 4; ++mt) {
        bf16x8 af = (sl == 0) ? hi[mt].h : hj[mt].h;
#pragma unroll
        for (int nt = 0; nt < 4; ++nt)
          acc[mt][nt] = __builtin_amdgcn_mfma_f32_16x16x32_bf16(af, bf[sl][nt].h, acc[mt][nt], 0, 0, 0);
      }
    }
#pragma unroll
    for (int mt = 0; mt < 4; ++mt) {
      const unsigned hw[4] = {hi[mt].u.x, hi[mt].u.y, hi[mt].u.z, hi[mt].u.w};
      const unsigned jw[4] = {hj[mt].u.x, hj[mt].u.y, hj[mt].u.z, hj[mt].u.w};
      unsigned d[4], pr[4];
#pragma unroll
      for (int w = 0; w < 4; ++w) {
        float i0 = bflo(hw[w]), i1 = bfhi(hw[w]);
        float j0 = bflo(jw[w]), j1 = bfhi(jw[w]);
        d[w] = perm_pack(i0 - j0, i1 - j1) & 0x7fff7fffu;
        pr[w] = perm_pack(i0 * j0, i1 * j1);
      }
      V16 a2, a3;
      a2.u = make_uint4(d[0], d[1], d[2], d[3]);
      a3.u = make_uint4(pr[0], pr[1], pr[2], pr[3]);
#pragma unroll
      for (int nt = 0; nt < 4; ++nt)
        acc[mt][nt] = __builtin_amdgcn_mfma_f32_16x16x32_bf16(a2.h, bf[2][nt].h, acc[mt][nt], 0, 0, 0);
#pragma unroll
      for (int nt = 0; nt < 4; ++nt)
        acc[mt][nt] = __builtin_amdgcn_mfma_f32_16x16x32_bf16(a3.h, bf[3][nt].h, acc[mt][nt], 0, 0, 0);
    }
    w1s += 131072;
  };

  stage_chunk(0);
  __syncthreads();
#pragma unroll 2
  for (int st4 = 0; st4 < 4; ++st4) kstep(st4);

  __syncthreads();       // all reads of chunk 0 done
  stage_chunk(1);
  __syncthreads();       // chunk 1 visible (compiler drains vmcnt here)
#pragma unroll 2
  for (int st4 = 0; st4 < 4; ++st4) kstep(st4);

  // ---- epilogue: bias + ReLU + W2, 16-lane shuffle reduce, atomic out ----
#pragma unroll
  for (int mt = 0; mt < 4; ++mt) {
    float pc0[4] = {0.f, 0.f, 0.f, 0.f};
    float pc1[4] = {0.f, 0.f, 0.f, 0.f};
#pragma unroll
    for (int nt = 0; nt < 4; ++nt) {
      int gc = n0 + nt * 16 + l16;
      float b1v = b1[gc];
      float w20 = w2[gc * 2 + 0];
      float w21 = w2[gc * 2 + 1];
#pragma unroll
      for (int r = 0; r < 4; ++r) {
        float v = fmaxf(acc[mt][nt][r] + b1v, 0.f);
        pc0[r] = fmaf(v, w20, pc0[r]);
        pc1[r] = fmaf(v, w21, pc1[r]);
      }
    }
#pragma unroll
    for (int r = 0; r < 4; ++r) {
      float s0 = pc0[r], s1 = pc1[r];
#pragma unroll
      for (int off = 1; off < 16; off <<= 1) {
        s0 += __shfl_xor(s0, off);
        s1 += __shfl_xor(s1, off);
      }
      int e = row0 + mt * 16 + quad * 4 + r;  // C/D: row = quad*4 + r
      if (l16 == 0) unsafeAtomicAdd(&out[(size_t)e * 2 + 0], s0);
      if (l16 == 1) unsafeAtomicAdd(&out[(size_t)e * 2 + 1], s1);
    }
  }
}

extern "C" void kernel_launch(void* const* d_in, const int* in_sizes, int n_in,
                              void* d_out, int out_size, void* d_ws, size_t ws_size,
                              hipStream_t stream) {
  const float* node = (const float*)d_in[0];
  const int* src = (const int*)d_in[1];
  const int* dst = (const int*)d_in[2];
  const float* W1 = (const float*)d_in[3];
  const float* b1 = (const float*)d_in[4];
  const float* W2 = (const float*)d_in[5];
  const float* b2 = (const float*)d_in[6];
  float* out = (float*)d_out;

  unsigned short* nodeb = (unsigned short*)d_ws;                      // 25,600,000 B
  unsigned short* w1pp2 = (unsigned short*)((char*)d_ws + 25600000);  // 1,048,576 B

  cvt_node_kernel<<<6250, 256, 0, stream>>>(node, nodeb);
  prep_w1pp2_kernel<<<256, 256, 0, stream>>>(W1, w1pp2);
  init_out_kernel<<<1024, 256, 0, stream>>>(out, b2);
  edge_mlp_kernel<<<8192, 256, 0, stream>>>(nodeb, w1pp2, src, dst, b1, W2, out);
}

// Round 5
// 416.982 us; speedup vs baseline: 4.4681x; 1.1241x over previous
//
#include <hip/hip_runtime.h>

#define N_NODES 50000
#define E_EDGES 262144

typedef __attribute__((ext_vector_type(8))) _Float16 f16x8;
typedef __attribute__((ext_vector_type(2))) _Float16 f16x2;
typedef __attribute__((ext_vector_type(4))) float f32x4;

union V16 { uint4 u; f16x8 h; };
union U32 { unsigned u; f16x2 p; };

// pack two f32 -> two f16 (RNE), a in low half
__device__ __forceinline__ unsigned h2pack(float a, float b) {
  union { _Float16 h[2]; unsigned u; } r;
  r.h[0] = (_Float16)a;
  r.h[1] = (_Float16)b;
  return r.u;
}
__device__ __forceinline__ void async_gather16(const void* gptr, void* lptr) {
  __builtin_amdgcn_global_load_lds(
      (const __attribute__((address_space(1))) void*)gptr,
      (__attribute__((address_space(3))) void*)lptr, 16, 0, 0);
}

// ---- prep: node_repr fp32 -> fp16 (RNE) ----
__global__ void cvt_node_kernel(const float* __restrict__ x, unsigned short* __restrict__ y) {
  int i = (blockIdx.x * 256 + threadIdx.x) * 8;
  float4 f0 = *(const float4*)(x + i);
  float4 f1 = *(const float4*)(x + i + 4);
  uint4 o;
  o.x = h2pack(f0.x, f0.y);
  o.y = h2pack(f0.z, f0.w);
  o.z = h2pack(f1.x, f1.y);
  o.w = h2pack(f1.z, f1.w);
  *(uint4*)(y + i) = o;
}

// ---- prep: W1 (1024x512 row-major in->out) -> W1pp2 fp16, 16-B units laid out
// [step(8)][sq=s*4+quad(16)][col(512)], unit = W1[k0..k0+8)[col], k0=s*256+step*32+quad*8
__global__ void prep_w1pp2_kernel(const float* __restrict__ w1, unsigned short* __restrict__ w1pp2) {
  int t = blockIdx.x * 256 + threadIdx.x;  // 65536 units
  int step = t >> 13;
  int rem = t & 8191;
  int sq = rem >> 9;
  int col = rem & 511;
  int s = sq >> 2, qd = sq & 3;
  int k0 = s * 256 + step * 32 + qd * 8;
  float f[8];
#pragma unroll
  for (int i = 0; i < 8; ++i) f[i] = w1[(size_t)(k0 + i) * 512 + col];
  uint4 o;
  o.x = h2pack(f[0], f[1]);
  o.y = h2pack(f[2], f[3]);
  o.z = h2pack(f[4], f[5]);
  o.w = h2pack(f[6], f[7]);
  *(uint4*)(w1pp2 + (size_t)t * 8) = o;
}

// ---- prep: out[e][c] = b2[c] ----
__global__ void init_out_kernel(float* __restrict__ out, const float* __restrict__ b2) {
  int i = blockIdx.x * 256 + threadIdx.x;
  float2 v; v.x = b2[0]; v.y = b2[1];
  *(float2*)(out + (size_t)i * 2) = v;
}

// ---- main fused kernel: block = 64 edges x 256 cols; ALL of A staged once (64 KB LDS),
//      ONE barrier; K-loop barrier-free, B streamed with fine vmcnt. (R0 structure —
//      LDS-chunking (R4) and 512-thr (R1/R2) both regressed; occupancy pinned ~21%
//      regardless of LDS, so latency must be hidden intra-wave, not by residency.)
//      R5 change: bf16 -> fp16 datapath. a2/a3 built with packed v_pk_sub/mul_f16 +
//      sign-mask abs: ~48 VALU/K-step vs ~176 for the f32-unpack bf16 path. VALUBusy
//      was 55% > MfmaUtil 35% — a2/a3 build was the co-critical path. ----
__global__ __launch_bounds__(256) void edge_mlp_kernel(
    const unsigned short* __restrict__ nodeb,  // [50000][256] fp16
    const unsigned short* __restrict__ w1pp2,  // repacked W1 (see prep)
    const int* __restrict__ src,
    const int* __restrict__ dst,
    const float* __restrict__ b1,
    const float* __restrict__ w2,   // [512][2] fp32
    float* __restrict__ out) {      // [E][2] fp32, pre-init with b2
  // hi: [0,32K) — 64 edges x 512 B; hj: [32K,64K)
  // 16-B unit slot for (e, st, q): e*32 + ((st*4+q) ^ (e&7))
  __shared__ char smem[65536];

  const int tid = threadIdx.x;
  const int wid = tid >> 6;
  const int lane = tid & 63;
  const int quad = lane >> 4;
  const int l16 = lane & 15;
  const int bx = blockIdx.x;
  // XCD swizzle: xc = bx&7; n-siblings + neighbor m-tiles share an XCD
  const int xc = bx & 7;
  const int t2 = bx >> 3;
  const int n_half = t2 & 1;                 // 0..1 (256-col halves)
  const int m_idx = (t2 >> 1) * 8 + xc;      // 0..4095 (64-edge tiles)
  const int row0 = m_idx * 64;
  const int n0 = n_half * 256 + wid * 64;

  const char* nodeB = (const char*)nodeb;
  const char* w1B = (const char*)w1pp2;

  // ---- B register-load offsets: (s*4+quad)*8192 + (n0+l16)*16 (+ step*131072) ----
  unsigned bOff[4];
#pragma unroll
  for (int s = 0; s < 4; ++s)
    bOff[s] = (unsigned)((s * 4 + quad) * 8192 + (n0 + l16) * 16);
  const char* w1s = w1B;

  // ---- A reader base: byte = (mt*16+l16)*512 + (((st*4+q)^(l16&7))<<4) ----
  const unsigned aXor = (unsigned)(l16 & 7);
  const unsigned aBase = (unsigned)(l16 * 512);

  f32x4 acc[4][4];
#pragma unroll
  for (int mt = 0; mt < 4; ++mt)
#pragma unroll
    for (int nt = 0; nt < 4; ++nt)
      acc[mt][nt] = (f32x4){0.f, 0.f, 0.f, 0.f};

  // ---- prologue: stage ALL of A (hi+hj, 64 edges x 512 B each region) ----
  // call c stages slots v = c*256+tid; e = v>>5 = c*8 + (tid>>5); w = (tid&31)^(e&7)
  {
    const int eh = tid >> 5;
    const unsigned wsw = (unsigned)(((tid & 31) ^ (eh & 7)) << 4);  // e&7 == eh&7 since c*8 aligned
#pragma unroll
    for (int c = 0; c < 8; ++c) {
      int e = c * 8 + eh;
      unsigned so = ((unsigned)src[row0 + e] << 9) + wsw;
      unsigned do_ = ((unsigned)dst[row0 + e] << 9) + wsw;
      async_gather16(nodeB + so, smem + c * 4096 + wid * 1024);
      async_gather16(nodeB + do_, smem + 32768 + c * 4096 + wid * 1024);
    }
  }
  __syncthreads();  // the ONLY barrier

#pragma unroll 2
  for (int step = 0; step < 8; ++step) {
    // B(t) loads — compiler emits fine-grained vmcnt; with unroll-2, B(t+1) overlaps MFMAs
    V16 bf[4][4];
#pragma unroll
    for (int s = 0; s < 4; ++s)
#pragma unroll
      for (int nt = 0; nt < 4; ++nt)
        bf[s][nt].u = *(const uint4*)(w1s + bOff[s] + nt * 256);
    // A fragments from LDS (read-only, no sync needed)
    const unsigned stq = (unsigned)(step * 4 + quad);
    V16 hi[4], hj[4];
#pragma unroll
    for (int mt = 0; mt < 4; ++mt) {
      unsigned ao = (unsigned)(mt * 16 * 512) + aBase + ((stq ^ aXor) << 4);
      hi[mt].u = *(const uint4*)(smem + ao);
      hj[mt].u = *(const uint4*)(smem + 32768 + ao);
    }
    // MFMA s=0 (hi), s=1 (hj)
#pragma unroll
    for (int sl = 0; sl < 2; ++sl) {
#pragma unroll
      for (int mt = 0; mt < 4; ++mt) {
        f16x8 af = (sl == 0) ? hi[mt].h : hj[mt].h;
#pragma unroll
        for (int nt = 0; nt < 4; ++nt)
          acc[mt][nt] = __builtin_amdgcn_mfma_f32_16x16x32_f16(af, bf[sl][nt].h, acc[mt][nt], 0, 0, 0);
      }
    }
    // build a2=|hi-hj|, a3=hi*hj with packed fp16 ops (3 VALU per word), MFMA s=2,3
#pragma unroll
    for (int mt = 0; mt < 4; ++mt) {
      const unsigned hw[4] = {hi[mt].u.x, hi[mt].u.y, hi[mt].u.z, hi[mt].u.w};
      const unsigned jw[4] = {hj[mt].u.x, hj[mt].u.y, hj[mt].u.z, hj[mt].u.w};
      unsigned d[4], pr[4];
#pragma unroll
      for (int w = 0; w < 4; ++w) {
        U32 hx, jx, dd, pp;
        hx.u = hw[w];
        jx.u = jw[w];
        dd.p = hx.p - jx.p;            // v_pk_add_f16 (neg mod)
        d[w] = dd.u & 0x7fff7fffu;     // abs: clear sign bits (exact)
        pp.p = hx.p * jx.p;            // v_pk_mul_f16
        pr[w] = pp.u;
      }
      V16 a2, a3;
      a2.u = make_uint4(d[0], d[1], d[2], d[3]);
      a3.u = make_uint4(pr[0], pr[1], pr[2], pr[3]);
#pragma unroll
      for (int nt = 0; nt < 4; ++nt)
        acc[mt][nt] = __builtin_amdgcn_mfma_f32_16x16x32_f16(a2.h, bf[2][nt].h, acc[mt][nt], 0, 0, 0);
#pragma unroll
      for (int nt = 0; nt < 4; ++nt)
        acc[mt][nt] = __builtin_amdgcn_mfma_f32_16x16x32_f16(a3.h, bf[3][nt].h, acc[mt][nt], 0, 0, 0);
    }
    w1s += 131072;
  }

  // ---- epilogue: bias + ReLU + W2, 16-lane shuffle reduce, atomic out ----
#pragma unroll
  for (int mt = 0; mt < 4; ++mt) {
    float pc0[4] = {0.f, 0.f, 0.f, 0.f};
    float pc1[4] = {0.f, 0.f, 0.f, 0.f};
#pragma unroll
    for (int nt = 0; nt < 4; ++nt) {
      int gc = n0 + nt * 16 + l16;
      float b1v = b1[gc];
      float w20 = w2[gc * 2 + 0];
      float w21 = w2[gc * 2 + 1];
#pragma unroll
      for (int r = 0; r < 4; ++r) {
        float v = fmaxf(acc[mt][nt][r] + b1v, 0.f);
        pc0[r] = fmaf(v, w20, pc0[r]);
        pc1[r] = fmaf(v, w21, pc1[r]);
      }
    }
#pragma unroll
    for (int r = 0; r < 4; ++r) {
      float s0 = pc0[r], s1 = pc1[r];
#pragma unroll
      for (int off = 1; off < 16; off <<= 1) {
        s0 += __shfl_xor(s0, off);
        s1 += __shfl_xor(s1, off);
      }
      int e = row0 + mt * 16 + quad * 4 + r;  // C/D: row = quad*4 + r
      if (l16 == 0) unsafeAtomicAdd(&out[(size_t)e * 2 + 0], s0);
      if (l16 == 1) unsafeAtomicAdd(&out[(size_t)e * 2 + 1], s1);
    }
  }
}

extern "C" void kernel_launch(void* const* d_in, const int* in_sizes, int n_in,
                              void* d_out, int out_size, void* d_ws, size_t ws_size,
                              hipStream_t stream) {
  const float* node = (const float*)d_in[0];
  const int* src = (const int*)d_in[1];
  const int* dst = (const int*)d_in[2];
  const float* W1 = (const float*)d_in[3];
  const float* b1 = (const float*)d_in[4];
  const float* W2 = (const float*)d_in[5];
  const float* b2 = (const float*)d_in[6];
  float* out = (float*)d_out;

  unsigned short* nodeb = (unsigned short*)d_ws;                      // 25,600,000 B
  unsigned short* w1pp2 = (unsigned short*)((char*)d_ws + 25600000);  // 1,048,576 B

  cvt_node_kernel<<<6250, 256, 0, stream>>>(node, nodeb);
  prep_w1pp2_kernel<<<256, 256, 0, stream>>>(W1, w1pp2);
  init_out_kernel<<<1024, 256, 0, stream>>>(out, b2);
  edge_mlp_kernel<<<8192, 256, 0, stream>>>(nodeb, w1pp2, src, dst, b1, W2, out);
}

// Round 6
// 415.611 us; speedup vs baseline: 4.4828x; 1.0033x over previous
//
#include <hip/hip_runtime.h>

#define N_NODES 50000
#define E_EDGES 262144

typedef __attribute__((ext_vector_type(8))) _Float16 f16x8;
typedef __attribute__((ext_vector_type(2))) _Float16 f16x2;
typedef __attribute__((ext_vector_type(4))) float f32x4;

union V16 { uint4 u; f16x8 h; };
union U32 { unsigned u; f16x2 p; };

// pack two f32 -> two f16 (RNE), a in low half
__device__ __forceinline__ unsigned h2pack(float a, float b) {
  union { _Float16 h[2]; unsigned u; } r;
  r.h[0] = (_Float16)a;
  r.h[1] = (_Float16)b;
  return r.u;
}
__device__ __forceinline__ void async_gather16(const void* gptr, void* lptr) {
  __builtin_amdgcn_global_load_lds(
      (const __attribute__((address_space(1))) void*)gptr,
      (__attribute__((address_space(3))) void*)lptr, 16, 0, 0);
}

// ---- prep: node_repr fp32 -> fp16 (RNE) ----
__global__ void cvt_node_kernel(const float* __restrict__ x, unsigned short* __restrict__ y) {
  int i = (blockIdx.x * 256 + threadIdx.x) * 8;
  float4 f0 = *(const float4*)(x + i);
  float4 f1 = *(const float4*)(x + i + 4);
  uint4 o;
  o.x = h2pack(f0.x, f0.y);
  o.y = h2pack(f0.z, f0.w);
  o.z = h2pack(f1.x, f1.y);
  o.w = h2pack(f1.z, f1.w);
  *(uint4*)(y + i) = o;
}

// ---- prep: W1 (1024x512 row-major in->out) -> W1pp2 fp16, 16-B units laid out
// [step(8)][sq=s*4+quad(16)][col(512)], unit = W1[k0..k0+8)[col], k0=s*256+step*32+quad*8
__global__ void prep_w1pp2_kernel(const float* __restrict__ w1, unsigned short* __restrict__ w1pp2) {
  int t = blockIdx.x * 256 + threadIdx.x;  // 65536 units
  int step = t >> 13;
  int rem = t & 8191;
  int sq = rem >> 9;
  int col = rem & 511;
  int s = sq >> 2, qd = sq & 3;
  int k0 = s * 256 + step * 32 + qd * 8;
  float f[8];
#pragma unroll
  for (int i = 0; i < 8; ++i) f[i] = w1[(size_t)(k0 + i) * 512 + col];
  uint4 o;
  o.x = h2pack(f[0], f[1]);
  o.y = h2pack(f[2], f[3]);
  o.z = h2pack(f[4], f[5]);
  o.w = h2pack(f[6], f[7]);
  *(uint4*)(w1pp2 + (size_t)t * 8) = o;
}

// ---- prep: out[e][c] = b2[c] ----
__global__ void init_out_kernel(float* __restrict__ out, const float* __restrict__ b2) {
  int i = blockIdx.x * 256 + threadIdx.x;
  float2 v; v.x = b2[0]; v.y = b2[1];
  *(float2*)(out + (size_t)i * 2) = v;
}

// ---- main fused kernel: block = 64 edges x 256 cols; ALL of A staged once (64 KB LDS),
//      ONE barrier; K-loop barrier-free. R6: EXPLICIT register double-buffering.
//      Evidence: R5 ran at VGPR=92 — too few to hold any prefetched B set, so every
//      K-step exposed a full L2 round-trip before its MFMAs (MfmaUtil 32%, both pipes
//      idle 2/3 of time, latency-bound). LDS pins residency at 2 waves/SIMD, so up to
//      256 VGPR/wave are free: spend them. b01 (s=0,1) + hi/hj double-buffered and
//      prefetched for t+1 BEFORE t's MFMAs; b23 (s=2,3) single-buffered at step start
//      (first use is after 32 MFMAs). All 8 steps hand-unrolled -> static reg indexing. ----
__global__ __launch_bounds__(256) void edge_mlp_kernel(
    const unsigned short* __restrict__ nodeb,  // [50000][256] fp16
    const unsigned short* __restrict__ w1pp2,  // repacked W1 (see prep)
    const int* __restrict__ src,
    const int* __restrict__ dst,
    const float* __restrict__ b1,
    const float* __restrict__ w2,   // [512][2] fp32
    float* __restrict__ out) {      // [E][2] fp32, pre-init with b2
  // hi: [0,32K) — 64 edges x 512 B; hj: [32K,64K)
  // 16-B unit slot for (e, st, q): e*32 + ((st*4+q) ^ (e&7))
  __shared__ char smem[65536];

  const int tid = threadIdx.x;
  const int wid = tid >> 6;
  const int lane = tid & 63;
  const int quad = lane >> 4;
  const int l16 = lane & 15;
  const int bx = blockIdx.x;
  // XCD swizzle: xc = bx&7; n-siblings + neighbor m-tiles share an XCD
  const int xc = bx & 7;
  const int t2 = bx >> 3;
  const int n_half = t2 & 1;                 // 0..1 (256-col halves)
  const int m_idx = (t2 >> 1) * 8 + xc;      // 0..4095 (64-edge tiles)
  const int row0 = m_idx * 64;
  const int n0 = n_half * 256 + wid * 64;

  const char* nodeB = (const char*)nodeb;
  const char* w1B = (const char*)w1pp2;

  // ---- B register-load offsets: (s*4+quad)*8192 + (n0+l16)*16 (+ step*131072) ----
  unsigned bOff[4];
#pragma unroll
  for (int s = 0; s < 4; ++s)
    bOff[s] = (unsigned)((s * 4 + quad) * 8192 + (n0 + l16) * 16);

  // ---- A reader base: byte = (mt*16+l16)*512 + (((st*4+q)^(l16&7))<<4) ----
  const unsigned aXor = (unsigned)(l16 & 7);
  const unsigned aBase = (unsigned)(l16 * 512);

  f32x4 acc[4][4];
#pragma unroll
  for (int mt = 0; mt < 4; ++mt)
#pragma unroll
    for (int nt = 0; nt < 4; ++nt)
      acc[mt][nt] = (f32x4){0.f, 0.f, 0.f, 0.f};

  // ---- prologue: stage ALL of A (hi+hj, 64 edges x 512 B each region) ----
  // call c stages slots v = c*256+tid; e = v>>5 = c*8 + (tid>>5); w = (tid&31)^(e&7)
  {
    const int eh = tid >> 5;
    const unsigned wsw = (unsigned)(((tid & 31) ^ (eh & 7)) << 4);  // e&7 == eh&7 since c*8 aligned
#pragma unroll
    for (int c = 0; c < 8; ++c) {
      int e = c * 8 + eh;
      unsigned so = ((unsigned)src[row0 + e] << 9) + wsw;
      unsigned do_ = ((unsigned)dst[row0 + e] << 9) + wsw;
      async_gather16(nodeB + so, smem + c * 4096 + wid * 1024);
      async_gather16(nodeB + do_, smem + 32768 + c * 4096 + wid * 1024);
    }
  }
  __syncthreads();  // the ONLY barrier

  // ---- explicit double-buffered K-loop state ----
  V16 b01[2][2][4];   // [buf][s(0..1)][nt]  — prefetched one step ahead
  V16 b23[2][4];      // [s-2][nt]           — loaded at step start (used late)
  V16 hiR[2][4], hjR[2][4];  // [buf][mt]    — prefetched one step ahead

  auto loadB01 = [&](int step, int buf) {
#pragma unroll
    for (int s = 0; s < 2; ++s)
#pragma unroll
      for (int nt = 0; nt < 4; ++nt)
        b01[buf][s][nt].u = *(const uint4*)(w1B + (unsigned)step * 131072u + bOff[s] + nt * 256);
  };
  auto loadB23 = [&](int step) {
#pragma unroll
    for (int s = 0; s < 2; ++s)
#pragma unroll
      for (int nt = 0; nt < 4; ++nt)
        b23[s][nt].u = *(const uint4*)(w1B + (unsigned)step * 131072u + bOff[s + 2] + nt * 256);
  };
  auto loadA = [&](int step, int buf) {
    const unsigned stq = (unsigned)(step * 4 + quad);
#pragma unroll
    for (int mt = 0; mt < 4; ++mt) {
      unsigned ao = (unsigned)(mt * 16 * 512) + aBase + ((stq ^ aXor) << 4);
      hiR[buf][mt].u = *(const uint4*)(smem + ao);
      hjR[buf][mt].u = *(const uint4*)(smem + 32768 + ao);
    }
  };

  loadB01(0, 0);
  loadA(0, 0);

#pragma unroll
  for (int step = 0; step < 8; ++step) {
    const int cur = step & 1;        // step is a literal under full unroll -> static idx
    const int nxt = cur ^ 1;
    loadB23(step);                   // used after 32 MFMAs — latency covered
    if (step < 7) {
      loadB01(step + 1, nxt);        // prefetch next-step B (s=0,1) before any MFMA
      loadA(step + 1, nxt);          // prefetch next-step A fragments from LDS
    }
    // MFMA s=0 (hi), s=1 (hj) — operands loaded during the PREVIOUS step
#pragma unroll
    for (int mt = 0; mt < 4; ++mt)
#pragma unroll
      for (int nt = 0; nt < 4; ++nt)
        acc[mt][nt] = __builtin_amdgcn_mfma_f32_16x16x32_f16(hiR[cur][mt].h, b01[cur][0][nt].h, acc[mt][nt], 0, 0, 0);
#pragma unroll
    for (int mt = 0; mt < 4; ++mt)
#pragma unroll
      for (int nt = 0; nt < 4; ++nt)
        acc[mt][nt] = __builtin_amdgcn_mfma_f32_16x16x32_f16(hjR[cur][mt].h, b01[cur][1][nt].h, acc[mt][nt], 0, 0, 0);
    // build a2=|hi-hj|, a3=hi*hj with packed fp16 (3 VALU per word), MFMA s=2,3
#pragma unroll
    for (int mt = 0; mt < 4; ++mt) {
      const unsigned hw[4] = {hiR[cur][mt].u.x, hiR[cur][mt].u.y, hiR[cur][mt].u.z, hiR[cur][mt].u.w};
      const unsigned jw[4] = {hjR[cur][mt].u.x, hjR[cur][mt].u.y, hjR[cur][mt].u.z, hjR[cur][mt].u.w};
      unsigned d[4], pr[4];
#pragma unroll
      for (int w = 0; w < 4; ++w) {
        U32 hx, jx, dd, pp;
        hx.u = hw[w];
        jx.u = jw[w];
        dd.p = hx.p - jx.p;            // v_pk_add_f16 (neg mod)
        d[w] = dd.u & 0x7fff7fffu;     // abs: clear sign bits (exact)
        pp.p = hx.p * jx.p;            // v_pk_mul_f16
        pr[w] = pp.u;
      }
      V16 a2, a3;
      a2.u = make_uint4(d[0], d[1], d[2], d[3]);
      a3.u = make_uint4(pr[0], pr[1], pr[2], pr[3]);
#pragma unroll
      for (int nt = 0; nt < 4; ++nt)
        acc[mt][nt] = __builtin_amdgcn_mfma_f32_16x16x32_f16(a2.h, b23[0][nt].h, acc[mt][nt], 0, 0, 0);
#pragma unroll
      for (int nt = 0; nt < 4; ++nt)
        acc[mt][nt] = __builtin_amdgcn_mfma_f32_16x16x32_f16(a3.h, b23[1][nt].h, acc[mt][nt], 0, 0, 0);
    }
  }

  // ---- epilogue: bias + ReLU + W2, 16-lane shuffle reduce, atomic out ----
#pragma unroll
  for (int mt = 0; mt < 4; ++mt) {
    float pc0[4] = {0.f, 0.f, 0.f, 0.f};
    float pc1[4] = {0.f, 0.f, 0.f, 0.f};
#pragma unroll
    for (int nt = 0; nt < 4; ++nt) {
      int gc = n0 + nt * 16 + l16;
      float b1v = b1[gc];
      float w20 = w2[gc * 2 + 0];
      float w21 = w2[gc * 2 + 1];
#pragma unroll
      for (int r = 0; r < 4; ++r) {
        float v = fmaxf(acc[mt][nt][r] + b1v, 0.f);
        pc0[r] = fmaf(v, w20, pc0[r]);
        pc1[r] = fmaf(v, w21, pc1[r]);
      }
    }
#pragma unroll
    for (int r = 0; r < 4; ++r) {
      float s0 = pc0[r], s1 = pc1[r];
#pragma unroll
      for (int off = 1; off < 16; off <<= 1) {
        s0 += __shfl_xor(s0, off);
        s1 += __shfl_xor(s1, off);
      }
      int e = row0 + mt * 16 + quad * 4 + r;  // C/D: row = quad*4 + r
      if (l16 == 0) unsafeAtomicAdd(&out[(size_t)e * 2 + 0], s0);
      if (l16 == 1) unsafeAtomicAdd(&out[(size_t)e * 2 + 1], s1);
    }
  }
}

extern "C" void kernel_launch(void* const* d_in, const int* in_sizes, int n_in,
                              void* d_out, int out_size, void* d_ws, size_t ws_size,
                              hipStream_t stream) {
  const float* node = (const float*)d_in[0];
  const int* src = (const int*)d_in[1];
  const int* dst = (const int*)d_in[2];
  const float* W1 = (const float*)d_in[3];
  const float* b1 = (const float*)d_in[4];
  const float* W2 = (const float*)d_in[5];
  const float* b2 = (const float*)d_in[6];
  float* out = (float*)d_out;

  unsigned short* nodeb = (unsigned short*)d_ws;                      // 25,600,000 B
  unsigned short* w1pp2 = (unsigned short*)((char*)d_ws + 25600000);  // 1,048,576 B

  cvt_node_kernel<<<6250, 256, 0, stream>>>(node, nodeb);
  prep_w1pp2_kernel<<<256, 256, 0, stream>>>(W1, w1pp2);
  init_out_kernel<<<1024, 256, 0, stream>>>(out, b2);
  edge_mlp_kernel<<<8192, 256, 0, stream>>>(nodeb, w1pp2, src, dst, b1, W2, out);
}